// Round 1
// baseline (17.550 us; speedup 1.0000x reference)
//
#include <hip/hip_runtime.h>
#include <hip/hip_bf16.h>

typedef __attribute__((ext_vector_type(4))) float f32x4;
typedef __attribute__((ext_vector_type(8))) short bf16x8;
typedef __attribute__((ext_vector_type(4))) short bf16x4;

#define DEVFN static __device__ __forceinline__

constexpr int Mdim = 4096;
constexpr int Ndim = 512;    // output cols
constexpr int Dk   = 512;    // K of each source matrix
constexpr int BM = 128, BN = 64, BK = 64;
constexpr int NKT = (2 * Dk) / BK;  // 16 K-tiles over the virtual K=1024 concat
constexpr float W_S = 0.6224593312018546f;   // sigmoid(0.5), compile-time const
constexpr float W_L = 1.0f - W_S;

DEVFN short f2bf(float x) {
    __hip_bfloat16 h = __float2bfloat16(x);   // RNE
    return *reinterpret_cast<short*>(&h);
}

// XOR swizzle: rows are 128B (64 bf16). Spreads the 16-lane same-column read
// across 8 16B slots -> 2-way bank aliasing (free). Bijective per row.
DEVFN int swz(int row, int colByte) {
    return row * 128 + (colByte ^ ((row & 7) << 4));
}

__global__ __launch_bounds__(512, 2)
void fused_proj_kernel(const float* __restrict__ S, const float* __restrict__ L,
                       const float* __restrict__ Ws, const float* __restrict__ Wl,
                       const float* __restrict__ bs, const float* __restrict__ bl,
                       float* __restrict__ out)
{
    __shared__ char smA[2][BM * BK * 2];   // 16 KB each
    __shared__ char smB[2][BN * BK * 2];   // 8 KB each

    const int tid  = threadIdx.x;
    const int bid  = blockIdx.x;
    // Mtile = bid&31: with round-robin XCD = bid%8, each XCD owns Mtiles
    // {x, x+8, x+16, x+24} across all Ntiles -> A rows reused within one XCD L2.
    const int Mtile = bid & 31;
    const int Ntile = bid >> 5;
    const int Mbase = Mtile * BM;
    const int Nbase = Ntile * BN;

    const int srow = tid >> 4;          // 0..31 staging row within a 32-row slab
    const int scol = (tid & 15) * 4;    // f32 col (0..60 step 4)
    const int lane = tid & 63;
    const int wid  = tid >> 6;          // 0..7
    const int wr   = wid >> 1;          // 0..3 -> 32-row slab
    const int wc   = wid & 1;           // 0..1 -> 32-col slab

    f32x4 acc[2][2];
#pragma unroll
    for (int m = 0; m < 2; ++m)
#pragma unroll
        for (int n = 0; n < 2; ++n)
            acc[m][n] = (f32x4)0.0f;

    float4 av[4];
    float4 bv[2];

    auto loadTiles = [&](int kt) {
        const float* sA = (kt < 8) ? S : L;
        const float* sB = (kt < 8) ? Ws : Wl;
        const int kOff = (kt & 7) * BK + scol;
#pragma unroll
        for (int q = 0; q < 4; ++q)
            av[q] = *(const float4*)(sA + (size_t)(Mbase + q * 32 + srow) * Dk + kOff);
#pragma unroll
        for (int q = 0; q < 2; ++q)
            bv[q] = *(const float4*)(sB + (size_t)(Nbase + q * 32 + srow) * Dk + kOff);
    };

    auto writeTiles = [&](int p, float scB) {
#pragma unroll
        for (int q = 0; q < 4; ++q) {
            bf16x4 v = { f2bf(av[q].x), f2bf(av[q].y), f2bf(av[q].z), f2bf(av[q].w) };
            *(bf16x4*)(&smA[p][swz(q * 32 + srow, scol * 2)]) = v;
        }
#pragma unroll
        for (int q = 0; q < 2; ++q) {
            bf16x4 v = { f2bf(bv[q].x * scB), f2bf(bv[q].y * scB),
                         f2bf(bv[q].z * scB), f2bf(bv[q].w * scB) };
            *(bf16x4*)(&smB[p][swz(q * 32 + srow, scol * 2)]) = v;
        }
    };

    // Prologue: stage tile 0, prefetch tile 1 into regs.
    loadTiles(0);
    writeTiles(0, W_S);
    loadTiles(1);
    __syncthreads();

    for (int kt = 0; kt < NKT; ++kt) {
        const int p = kt & 1;
        // Compute tile kt from buf p.
#pragma unroll
        for (int kk = 0; kk < 2; ++kk) {
            bf16x8 a[2], b[2];
            const int cb = kk * 64 + (lane >> 4) * 16;   // 16B-aligned col byte
#pragma unroll
            for (int m = 0; m < 2; ++m)
                a[m] = *(const bf16x8*)(&smA[p][swz(wr * 32 + m * 16 + (lane & 15), cb)]);
#pragma unroll
            for (int n = 0; n < 2; ++n)
                b[n] = *(const bf16x8*)(&smB[p][swz(wc * 32 + n * 16 + (lane & 15), cb)]);
#pragma unroll
            for (int m = 0; m < 2; ++m)
#pragma unroll
                for (int n = 0; n < 2; ++n)
                    acc[m][n] = __builtin_amdgcn_mfma_f32_16x16x32_bf16(a[m], b[n], acc[m][n], 0, 0, 0);
        }
        if (kt + 1 < NKT) {
            // buf p^1 last read at iter kt-1; that iter's barrier makes this safe.
            writeTiles(p ^ 1, (kt + 1 < 8) ? W_S : W_L);
            if (kt + 2 < NKT) loadTiles(kt + 2);
            __syncthreads();   // writes visible before iter kt+1 reads buf p^1
        }
    }

    // Epilogue: bias + store. D layout: col = lane&15, row = (lane>>4)*4 + r.
#pragma unroll
    for (int n = 0; n < 2; ++n) {
        const int j = Nbase + wc * 32 + n * 16 + (lane & 15);
        const float bias = W_S * bs[j] + W_L * bl[j];
#pragma unroll
        for (int m = 0; m < 2; ++m) {
            const int i0 = Mbase + wr * 32 + m * 16 + ((lane >> 4) << 2);
#pragma unroll
            for (int r = 0; r < 4; ++r)
                out[(size_t)(i0 + r) * Ndim + j] = acc[m][n][r] + bias;
        }
    }
}

extern "C" void kernel_launch(void* const* d_in, const int* in_sizes, int n_in,
                              void* d_out, int out_size, void* d_ws, size_t ws_size,
                              hipStream_t stream) {
    const float* S  = (const float*)d_in[0];   // small_graph_features [4096,512]
    const float* L  = (const float*)d_in[1];   // large_graph_features [4096,512]
    const float* Ws = (const float*)d_in[2];   // W_small [512,512]
    const float* bs = (const float*)d_in[3];   // b_small [512]
    const float* Wl = (const float*)d_in[4];   // W_large [512,512]
    const float* bl = (const float*)d_in[5];   // b_large [512]
    // d_in[6] = sigma: output does not depend on it (HSIC/MMD are dead code).

    const int grid = (Mdim / BM) * (Ndim / BN);   // 32*8 = 256
    fused_proj_kernel<<<grid, 512, 0, stream>>>(S, L, Ws, Wl, bs, bl, (float*)d_out);
}